// Round 1
// baseline (762.902 us; speedup 1.0000x reference)
//
#include <hip/hip_runtime.h>

constexpr int NNODES = 100000;
constexpr int NEDGES = 1280000;

// ---------------------------------------------------------------------------
// Fused edge kernel: block of 256 threads handles 64 edges.
// Phase 1: load edge_feat rows (lane = feature), stage to LDS, and (optionally)
//          compute comp = ef * node_feat[src], scatter norm*comp into
//          accF/accR via HW f32 atomics.
// Phase 2: edge_out rows = Xs @ rel_weight, lane = output column, weight
//          column held in VGPRs, x broadcast from LDS as float4.
// ---------------------------------------------------------------------------
template <bool SCATTER>
__global__ __launch_bounds__(256) void edge_fused_kernel(
    const float* __restrict__ edge_feat,
    const float* __restrict__ node_feat,
    const float* __restrict__ edge_norm,
    const int*   __restrict__ src,
    const int*   __restrict__ dst,
    const int*   __restrict__ is_rev,
    const float* __restrict__ rel_w,
    float* __restrict__ accF,
    float* __restrict__ accR,
    float* __restrict__ edge_out)
{
    __shared__ float Xs[64][64];
    const int tid   = threadIdx.x;
    const int lane  = tid & 63;
    const int wv    = tid >> 6;
    const int ebase = blockIdx.x * 64;

    // Preload rel_weight column `lane` into registers (coalesced across lanes).
    float w[64];
#pragma unroll
    for (int k = 0; k < 64; ++k) w[k] = rel_w[k * 64 + lane];

    // ---- Phase 1: stage + scatter ----
#pragma unroll
    for (int i = 0; i < 16; ++i) {
        const int r = wv * 16 + i;
        const int e = ebase + r;
        const float ef = edge_feat[(size_t)e * 64 + lane];
        Xs[r][lane] = ef;
        if (SCATTER) {
            const int   s  = src[e];
            const int   d  = dst[e];
            const int   rv = is_rev[e];
            const float nm = edge_norm[e];
            const float comp = ef * node_feat[(size_t)s * 64 + lane];
            float* accp = rv ? accR : accF;
            unsafeAtomicAdd(accp + (size_t)d * 64 + lane, comp * nm);
        }
    }
    __syncthreads();

    // ---- Phase 2: edge_out = Xs @ rel_w ----
#pragma unroll 1
    for (int i = 0; i < 16; ++i) {
        const int r = wv * 16 + i;
        const float4* xr = (const float4*)(&Xs[r][0]);
        float a0 = 0.f, a1 = 0.f, a2 = 0.f, a3 = 0.f;
#pragma unroll
        for (int k4 = 0; k4 < 16; ++k4) {
            const float4 x = xr[k4];
            a0 += x.x * w[k4 * 4 + 0];
            a1 += x.y * w[k4 * 4 + 1];
            a2 += x.z * w[k4 * 4 + 2];
            a3 += x.w * w[k4 * 4 + 3];
        }
        edge_out[(size_t)(ebase + r) * 64 + lane] = (a0 + a1) + (a2 + a3);
    }
}

// ---------------------------------------------------------------------------
// Scatter-only kernel (fallback path): one thread per (edge, feature).
// ---------------------------------------------------------------------------
__global__ __launch_bounds__(256) void edge_scatter_kernel(
    const float* __restrict__ edge_feat,
    const float* __restrict__ node_feat,
    const float* __restrict__ edge_norm,
    const int*   __restrict__ src,
    const int*   __restrict__ dst,
    const int*   __restrict__ is_rev,
    float* __restrict__ accF,
    float* __restrict__ accR)
{
    const size_t t = (size_t)blockIdx.x * blockDim.x + threadIdx.x;
    if (t >= (size_t)NEDGES * 64) return;
    const int e    = (int)(t >> 6);
    const int lane = (int)(t & 63);

    const float ef   = edge_feat[(size_t)e * 64 + lane];
    const int   s    = src[e];
    const int   d    = dst[e];
    const int   rv   = is_rev[e];
    const float nm   = edge_norm[e];
    const float comp = ef * node_feat[(size_t)s * 64 + lane];
    float* accp = rv ? accR : accF;
    unsafeAtomicAdd(accp + (size_t)d * 64 + lane, comp * nm);
}

// ---------------------------------------------------------------------------
// Node kernel: block of 256 threads handles 64 nodes.
// node_out = (accF@Win + accR@Wout + node_feat@(diag(loop_rel)@Wl)) / 3 + bias
// Safe for in-place accF == node_out (each block reads only rows it writes,
// staged to LDS before any global write).
// ---------------------------------------------------------------------------
__global__ __launch_bounds__(256) void node_kernel(
    const float* __restrict__ accF,
    const float* __restrict__ accR,
    const float* __restrict__ node_feat,
    const float* __restrict__ in_w,
    const float* __restrict__ out_w,
    const float* __restrict__ loop_w,
    const float* __restrict__ loop_rel,
    const float* __restrict__ bias,
    float* __restrict__ node_out)
{
    __shared__ float XF[64][64];
    __shared__ float XR[64][64];
    __shared__ float XN[64][64];
    const int tid   = threadIdx.x;
    const int lane  = tid & 63;
    const int wv    = tid >> 6;
    const int nbase = blockIdx.x * 64;

    float wi[64], wo[64], wl[64];
#pragma unroll
    for (int k = 0; k < 64; ++k) {
        wi[k] = in_w[k * 64 + lane];
        wo[k] = out_w[k * 64 + lane];
        wl[k] = loop_w[k * 64 + lane] * loop_rel[k];
    }
    const float b = bias[lane];

#pragma unroll
    for (int i = 0; i < 16; ++i) {
        const int r = wv * 16 + i;
        const int n = nbase + r;
        if (n < NNODES) {
            XF[r][lane] = accF[(size_t)n * 64 + lane];
            XR[r][lane] = accR[(size_t)n * 64 + lane];
            XN[r][lane] = node_feat[(size_t)n * 64 + lane];
        }
    }
    __syncthreads();

#pragma unroll 1
    for (int i = 0; i < 16; ++i) {
        const int r = wv * 16 + i;
        const int n = nbase + r;
        if (n >= NNODES) continue;
        const float4* xf = (const float4*)(&XF[r][0]);
        const float4* xg = (const float4*)(&XR[r][0]);
        const float4* xh = (const float4*)(&XN[r][0]);
        float a0 = 0.f, a1 = 0.f, a2 = 0.f, a3 = 0.f;
#pragma unroll
        for (int k4 = 0; k4 < 16; ++k4) {
            const float4 f = xf[k4];
            const float4 g = xg[k4];
            const float4 h = xh[k4];
            a0 += f.x * wi[k4 * 4 + 0] + g.x * wo[k4 * 4 + 0] + h.x * wl[k4 * 4 + 0];
            a1 += f.y * wi[k4 * 4 + 1] + g.y * wo[k4 * 4 + 1] + h.y * wl[k4 * 4 + 1];
            a2 += f.z * wi[k4 * 4 + 2] + g.z * wo[k4 * 4 + 2] + h.z * wl[k4 * 4 + 2];
            a3 += f.w * wi[k4 * 4 + 3] + g.w * wo[k4 * 4 + 3] + h.w * wl[k4 * 4 + 3];
        }
        node_out[(size_t)n * 64 + lane] =
            ((a0 + a1) + (a2 + a3)) * 0.3333333f + b;
    }
}

// ---------------------------------------------------------------------------
extern "C" void kernel_launch(void* const* d_in, const int* in_sizes, int n_in,
                              void* d_out, int out_size, void* d_ws, size_t ws_size,
                              hipStream_t stream)
{
    const float* node_feat = (const float*)d_in[0];
    const float* edge_feat = (const float*)d_in[1];
    const float* edge_norm = (const float*)d_in[2];
    const int*   src       = (const int*)d_in[3];
    const int*   dst       = (const int*)d_in[4];
    const int*   is_rev    = (const int*)d_in[5];
    const float* in_w      = (const float*)d_in[6];
    const float* out_w     = (const float*)d_in[7];
    const float* rel_w     = (const float*)d_in[8];
    const float* loop_w    = (const float*)d_in[9];
    const float* loop_rel  = (const float*)d_in[10];
    const float* bias      = (const float*)d_in[11];

    float* node_out = (float*)d_out;
    float* edge_out = (float*)d_out + (size_t)NNODES * 64;

    const size_t accBytes = (size_t)NNODES * 64 * sizeof(float);
    const int nodeBlocks  = (NNODES + 63) / 64;
    const int edgeBlocks  = NEDGES / 64;

    if (ws_size >= 2 * accBytes) {
        // Fast path: accumulators in workspace, single pass over edge_feat.
        float* accF = (float*)d_ws;
        float* accR = accF + (size_t)NNODES * 64;
        hipMemsetAsync(d_ws, 0, 2 * accBytes, stream);
        edge_fused_kernel<true><<<edgeBlocks, 256, 0, stream>>>(
            edge_feat, node_feat, edge_norm, src, dst, is_rev, rel_w,
            accF, accR, edge_out);
        node_kernel<<<nodeBlocks, 256, 0, stream>>>(
            accF, accR, node_feat, in_w, out_w, loop_w, loop_rel, bias, node_out);
    } else {
        // Fallback: borrow d_out regions as accumulators.
        float* accF = node_out;   // overwritten in-place by node_kernel
        float* accR = edge_out;   // overwritten later by edge_fused_kernel
        hipMemsetAsync(accF, 0, accBytes, stream);
        hipMemsetAsync(accR, 0, accBytes, stream);
        edge_scatter_kernel<<<(int)(((size_t)NEDGES * 64 + 255) / 256), 256, 0, stream>>>(
            edge_feat, node_feat, edge_norm, src, dst, is_rev, accF, accR);
        node_kernel<<<nodeBlocks, 256, 0, stream>>>(
            accF, accR, node_feat, in_w, out_w, loop_w, loop_rel, bias, node_out);
        edge_fused_kernel<false><<<edgeBlocks, 256, 0, stream>>>(
            edge_feat, node_feat, edge_norm, src, dst, is_rev, rel_w,
            nullptr, nullptr, edge_out);
    }
}